// Round 7
// baseline (247.208 us; speedup 1.0000x reference)
//
#include <hip/hip_runtime.h>
#include <math.h>
#include <float.h>

#define NPIX 2304   // 48*48
#define NPAD 2500   // 50*50
#define PLANE 573440  // 2560*224 padded [p][d] plane per batch
#define MARGIN 3e-4f

// ws layout in floats
#define OFF_QP    0u          // [2][2560][224] fp32, p-major, zero-padded
#define OFF_KP    1146880u    // [2][2560][224]
#define OFF_NK    2293760u    // [2][2500]
#define OFF_INVNK 2298760u    // [2][2304]
#define OFF_PVAL  2303368u    // [2][48][2304] partial best
#define OFF_PSEC  2524552u    // [2][48][2304] partial second-best
#define OFF_PIDX  2745736u    // int [2][48][2304]
#define OFF_IDX   2966920u    // int [2][2304]
#define OFF_FLAG  2971528u    // int [2][2304]
#define OFF_FIXB  2976136u    // u64 [2][2304] (8B aligned)
#define OFF_S     2985352u    // [z][2500][2500]
#define OFF_SOFF  OFF_S       // int [2][9][2304] — aliases S (S dead by then)
#define SSTRIDE   6250000L

typedef __attribute__((ext_vector_type(8))) short short8;
typedef __attribute__((ext_vector_type(4))) float f32x4;

__device__ __forceinline__ unsigned short bfhi(float f) {
    unsigned u = __float_as_uint(f);
    return (unsigned short)((u + 0x7FFFu + ((u >> 16) & 1u)) >> 16);
}
__device__ __forceinline__ unsigned short bfcvt(float f, bool wantHi) {
    unsigned short h = bfhi(f);
    if (wantHi) return h;
    float hf = __uint_as_float(((unsigned)h) << 16);
    return bfhi(f - hf);
}

// ---------------- stage 1: q = W*x1, k = W*x2 -> [p][d] rows ----------------
__global__ __launch_bounds__(256) void k_qk(const float* __restrict__ x1,
                                            const float* __restrict__ x2,
                                            const float* __restrict__ W,
                                            float* __restrict__ qp,
                                            float* __restrict__ kp) {
    __shared__ float Ws[512];
    const int t = threadIdx.x;
    Ws[t] = W[t];
    Ws[t + 256] = W[t + 256];
    __syncthreads();
    const int img = blockIdx.x / 9;      // 0..49  (b*25 + a)
    const int chunk = blockIdx.x % 9;
    const int pix = chunk * 256 + t;     // 0..2303
    const int b = img / 25, a = img % 25;
    const int y = pix / 48, x = pix % 48;

    float q[8], k[8];
#pragma unroll
    for (int o = 0; o < 8; ++o) { q[o] = 0.f; k[o] = 0.f; }

    const float* p1 = x1 + (size_t)b * 64 * 57600 + a * 2304 + pix;
    const float* p2 = x2 + (size_t)b * 64 * 57600 + a * 2304 + pix;
    for (int c = 0; c < 64; ++c) {
        float v1 = p1[c * 57600];
        float v2 = p2[c * 57600];
#pragma unroll
        for (int o = 0; o < 8; ++o) {
            float w = Ws[o * 64 + c];
            q[o] = fmaf(w, v1, q[o]);
            k[o] = fmaf(w, v2, k[o]);
        }
    }
    const int p = (y + 1) * 50 + (x + 1);
    float* qd = qp + (size_t)b * PLANE + (size_t)p * 224 + a * 8;
    float* kd = kp + (size_t)b * PLANE + (size_t)p * 224 + a * 8;
    float4 q0 = { q[0], q[1], q[2], q[3] }, q1 = { q[4], q[5], q[6], q[7] };
    float4 k0 = { k[0], k[1], k[2], k[3] }, k1 = { k[4], k[5], k[6], k[7] };
    *(float4*)qd = q0; *(float4*)(qd + 4) = q1;
    *(float4*)kd = k0; *(float4*)(kd + 4) = k1;
}

// ---------------- per-position squared norms of k (row reads now) ----------------
__global__ void k_nk(const float* __restrict__ kp, float* __restrict__ nk) {
    int t = blockIdx.x * 256 + threadIdx.x;  // 0..4999
    if (t >= 2 * NPAD) return;
    int b = t / NPAD, p = t - b * NPAD;
    const float* src = kp + (size_t)b * PLANE + (size_t)p * 224;
    float s = 0.f;
    for (int d = 0; d < 200; d += 4) {
        float4 v = *(const float4*)(src + d);
        s = fmaf(v.x, v.x, s); s = fmaf(v.y, v.y, s);
        s = fmaf(v.z, v.z, s); s = fmaf(v.w, v.w, s);
    }
    nk[t] = s;
}

__global__ void k_invnk(const float* __restrict__ nk, float* __restrict__ invNk) {
    int t = blockIdx.x * 256 + threadIdx.x;  // 0..4607
    if (t >= 2 * NPIX) return;
    int b = t / NPIX, m = t - b * NPIX;
    int my = m / 48, mx = m % 48;
    const float* nb = nk + b * NPAD;
    float s = 0.f;
#pragma unroll
    for (int i = 0; i < 3; ++i)
#pragma unroll
        for (int j = 0; j < 3; ++j)
            s += nb[(my + i) * 50 + mx + j];
    invNk[t] = 1.0f / fmaxf(sqrtf(s), 1e-12f);
}

// ---- stage 2a: S ~= A^T B via 3-term bf16-split MFMA (hi*hi + hi*lo + lo*hi) ----
// K-concat: 21 steps of 32 d; term = ks/7 (A: hi,hi,lo / B: hi,lo,hi), d0=(ks%7)*32.
// LDS tiles [row][quad] with phys quad = q ^ (row&3) -> ~2-way conflicts (free).
__global__ __launch_bounds__(256, 2) void k_mfma(const float* __restrict__ qp,
                                                 const float* __restrict__ kp,
                                                 float* __restrict__ S,
                                                 long sStride, int bofs) {
    __shared__ short Abuf[2][4096];   // 128 rows x 32 d (bf16)
    __shared__ short Bbuf[2][4096];
    const int t = threadIdx.x;
    // XCD-aware bijective swizzle (nwg = 800 or 400, both %8==0)
    const int nwg = gridDim.x * gridDim.y * gridDim.z;
    const int lin = (blockIdx.z * gridDim.y + blockIdx.y) * gridDim.x + blockIdx.x;
    const int work = (lin & 7) * (nwg >> 3) + (lin >> 3);
    const int z = work / 400;
    const int rem = work - z * 400;
    const int wy = rem / 20, wx = rem - (rem / 20) * 20;

    const int batch = bofs + z;
    const float* A = qp + (size_t)batch * PLANE;
    const float* B = kp + (size_t)batch * PLANE;
    float* Sb = S + (size_t)z * sStride;
    const int p0 = wy * 128, r0 = wx * 128;

    // staging: 2 passes; pass pz -> row = pz*64 + (t>>2), quad = t&3
    const int srow = t >> 2, squad = t & 3;
    const int spq = squad ^ (srow & 3);       // phys quad (same for both passes)

    const int w = t >> 6, l = t & 63;
    const int wqp = (w >> 1) * 64, wqr = (w & 1) * 64;
    const int lp = l & 15;
    const int physq = (l >> 4) ^ (l & 3);

    f32x4 acc[4][4];
#pragma unroll
    for (int i = 0; i < 4; ++i)
#pragma unroll
        for (int j = 0; j < 4; ++j) acc[i][j] = (f32x4){0.f, 0.f, 0.f, 0.f};

    float4 ra0, ra1, ra2, ra3, rb0, rb1, rb2, rb3;

#define LOADS(ks)                                                              \
    {                                                                          \
        const int d0 = ((ks) % 7) * 32 + squad * 8;                            \
        const float* ap = A + (size_t)(p0 + srow) * 224 + d0;                  \
        const float* bp = B + (size_t)(r0 + srow) * 224 + d0;                  \
        ra0 = *(const float4*)ap;       ra1 = *(const float4*)(ap + 4);        \
        ra2 = *(const float4*)(ap + 64 * 224); ra3 = *(const float4*)(ap + 64 * 224 + 4); \
        rb0 = *(const float4*)bp;       rb1 = *(const float4*)(bp + 4);        \
        rb2 = *(const float4*)(bp + 64 * 224); rb3 = *(const float4*)(bp + 64 * 224 + 4); \
    }

#define PACK8(dst, v0, v1, useHi)                                              \
    {                                                                          \
        short8 vv;                                                             \
        vv[0] = (short)bfcvt(v0.x, useHi); vv[1] = (short)bfcvt(v0.y, useHi);  \
        vv[2] = (short)bfcvt(v0.z, useHi); vv[3] = (short)bfcvt(v0.w, useHi);  \
        vv[4] = (short)bfcvt(v1.x, useHi); vv[5] = (short)bfcvt(v1.y, useHi);  \
        vv[6] = (short)bfcvt(v1.z, useHi); vv[7] = (short)bfcvt(v1.w, useHi);  \
        *(short8*)(dst) = vv;                                                  \
    }

#define WRITE(buf, ks)                                                         \
    {                                                                          \
        const int term = (ks) / 7;                                             \
        const bool aHi = (term < 2), bHi = (term != 1);                        \
        PACK8(&Abuf[buf][srow * 32 + spq * 8], ra0, ra1, aHi);                 \
        PACK8(&Abuf[buf][(64 + srow) * 32 + spq * 8], ra2, ra3, aHi);          \
        PACK8(&Bbuf[buf][srow * 32 + spq * 8], rb0, rb1, bHi);                 \
        PACK8(&Bbuf[buf][(64 + srow) * 32 + spq * 8], rb2, rb3, bHi);          \
    }

    LOADS(0);
    WRITE(0, 0);
    __syncthreads();

    for (int ks = 0; ks < 21; ++ks) {
        const int cur = ks & 1;
        if (ks + 1 < 21) LOADS(ks + 1);
        {
            const short* Ab = &Abuf[cur][0];
            const short* Bb = &Bbuf[cur][0];
            short8 af[4], bfr[4];
#pragma unroll
            for (int tr = 0; tr < 4; ++tr)
                af[tr] = *(const short8*)(Ab + (wqp + tr * 16 + lp) * 32 + physq * 8);
#pragma unroll
            for (int tc = 0; tc < 4; ++tc)
                bfr[tc] = *(const short8*)(Bb + (wqr + tc * 16 + lp) * 32 + physq * 8);
#pragma unroll
            for (int tr = 0; tr < 4; ++tr)
#pragma unroll
                for (int tc = 0; tc < 4; ++tc)
                    acc[tr][tc] = __builtin_amdgcn_mfma_f32_16x16x32_bf16(
                        af[tr], bfr[tc], acc[tr][tc], 0, 0, 0);
        }
        if (ks + 1 < 21) {
            WRITE(cur ^ 1, ks + 1);
            __syncthreads();
        }
    }

    // D mapping: row = (l>>4)*4 + v, col = lp (per 16x16 tile)
#pragma unroll
    for (int tr = 0; tr < 4; ++tr) {
#pragma unroll
        for (int v = 0; v < 4; ++v) {
            const int p = p0 + wqp + tr * 16 + (l >> 4) * 4 + v;
            if (p < NPAD) {
                float* srow_ = Sb + (size_t)p * NPAD;
#pragma unroll
                for (int tc = 0; tc < 4; ++tc) {
                    const int c = r0 + wqr + tc * 16 + lp;
                    if (c < NPAD) srow_[c] = acc[tr][tc][v];
                }
            }
        }
    }
#undef LOADS
#undef PACK8
#undef WRITE
}

// -------- stage 2b: block per (my, ly, z); box-sum + partial top-2 argmax --------
__global__ __launch_bounds__(384) void k_argmax(const float* __restrict__ S,
                                                const float* __restrict__ invNk,
                                                float* __restrict__ pval,
                                                float* __restrict__ psec,
                                                int* __restrict__ pidx,
                                                long sStride, int bofs) {
    __shared__ float band[3][50][50];
    const int t = threadIdx.x;
    const int my = blockIdx.x;     // 0..47
    const int ly = blockIdx.y;     // 0..47
    const int batch = bofs + blockIdx.z;
    const float* Sb = S + (size_t)blockIdx.z * sStride;
    const int lx = t >> 3;         // 0..47
    const int mc = t & 7;          // 0..7

    for (int e = t; e < 7500; e += 384) {
        int i = e / 2500;
        int rem = e - i * 2500;
        int uu = rem / 50;
        int vv = rem - uu * 50;
        band[i][uu][vv] = Sb[(size_t)((ly + i) * 50 + uu) * NPAD + (my + i) * 50 + vv];
    }
    __syncthreads();

    const float* inb = invNk + batch * NPIX;
    float b1 = -FLT_MAX, b2 = -FLT_MAX;
    int i1 = 0x7FFFFFFF;

#pragma unroll
    for (int k = 0; k < 6; ++k) {
        int mx = mc + (k << 3);
        float s = 0.f;
#pragma unroll
        for (int i = 0; i < 3; ++i)
#pragma unroll
            for (int j = 0; j < 3; ++j)
                s += band[i][lx + j][mx + j];
        int m = my * 48 + mx;
        float v = s * inb[m];
        if (v > b1 || (v == b1 && m < i1)) { b2 = b1; b1 = v; i1 = m; }
        else b2 = fmaxf(b2, v);
    }
#pragma unroll
    for (int off = 1; off < 8; off <<= 1) {
        float ob1 = __shfl_xor(b1, off, 64);
        int oi1 = __shfl_xor(i1, off, 64);
        float ob2 = __shfl_xor(b2, off, 64);
        if (ob1 > b1 || (ob1 == b1 && oi1 < i1)) { b2 = fmaxf(b1, ob2); b1 = ob1; i1 = oi1; }
        else b2 = fmaxf(b2, ob1);
    }
    if (mc == 0) {
        int o = (batch * 48 + my) * NPIX + ly * 48 + lx;
        pval[o] = b1;
        psec[o] = b2;
        pidx[o] = i1;
    }
}

__global__ void k_argred(const float* __restrict__ pval, const float* __restrict__ psec,
                         const int* __restrict__ pidx, int* __restrict__ idxout,
                         int* __restrict__ flag) {
    int t = blockIdx.x * 256 + threadIdx.x;
    if (t >= 2 * NPIX) return;
    int b = t / NPIX, lcl = t - b * NPIX;
    float b1 = -FLT_MAX, b2 = -FLT_MAX;
    int i1 = 0x7FFFFFFF;
    for (int my = 0; my < 48; ++my) {
        int o = (b * 48 + my) * NPIX + lcl;
        float v1 = pval[o], v2 = psec[o];
        int ii = pidx[o];
        if (v1 > b1 || (v1 == b1 && ii < i1)) { b2 = fmaxf(b1, v2); b1 = v1; i1 = ii; }
        else b2 = fmaxf(b2, v1);
    }
    idxout[t] = i1;
    flag[t] = (b1 - b2 < MARGIN) ? 1 : 0;
}

// -------- exact fp32 recheck for flagged rows (reproduces exact-chain semantics) ----
__global__ __launch_bounds__(256) void k_fix(const float* __restrict__ qp,
                                             const float* __restrict__ kp,
                                             const float* __restrict__ invNk,
                                             const int* __restrict__ flag,
                                             unsigned long long* __restrict__ fixb) {
    const int lrow = blockIdx.x, h = blockIdx.y, b = blockIdx.z;
    if (!flag[b * NPIX + lrow]) return;
    __shared__ float qa[9][200];
    __shared__ float Srows[9][1300];
    __shared__ float rv[256];
    __shared__ int ri[256];
    const int t = threadIdx.x;
    const int ly = lrow / 48, lx = lrow % 48;
    const float* Ap = qp + (size_t)b * PLANE;
    const float* Bp = kp + (size_t)b * PLANE;
    for (int u = t; u < 1800; u += 256) {
        int ij = u / 200, d = u - ij * 200;
        int pr = (ly + ij / 3) * 50 + lx + (ij % 3);
        qa[ij][d] = Ap[(size_t)pr * 224 + d];
    }
    __syncthreads();
    const int cbase = 1200 * h;
    for (int c = t; c < 1300; c += 256) {
        const float* kr = Bp + (size_t)(cbase + c) * 224;
        float s[9];
#pragma unroll
        for (int ij = 0; ij < 9; ++ij) s[ij] = 0.f;
        for (int d = 0; d < 200; d += 4) {
            float4 kv = *(const float4*)(kr + d);
#pragma unroll
            for (int ij = 0; ij < 9; ++ij) {
                s[ij] = fmaf(qa[ij][d], kv.x, s[ij]);
                s[ij] = fmaf(qa[ij][d + 1], kv.y, s[ij]);
                s[ij] = fmaf(qa[ij][d + 2], kv.z, s[ij]);
                s[ij] = fmaf(qa[ij][d + 3], kv.w, s[ij]);
            }
        }
#pragma unroll
        for (int ij = 0; ij < 9; ++ij) Srows[ij][c] = s[ij];
    }
    __syncthreads();
    float bb = -FLT_MAX;
    int bi = 0x7FFFFFFF;
    const float* inb = invNk + b * NPIX;
    for (int u = t; u < 1152; u += 256) {
        int my = h * 24 + u / 48, mx = u - (u / 48) * 48;
        float ssum = 0.f;
#pragma unroll
        for (int i = 0; i < 3; ++i)
#pragma unroll
            for (int j = 0; j < 3; ++j)
                ssum += Srows[i * 3 + j][(my + i) * 50 + mx + j - cbase];
        int m = my * 48 + mx;
        float v = ssum * inb[m];
        if (v > bb || (v == bb && m < bi)) { bb = v; bi = m; }
    }
    rv[t] = bb; ri[t] = bi;
    __syncthreads();
    for (int s2 = 128; s2 > 0; s2 >>= 1) {
        if (t < s2) {
            float ov = rv[t + s2]; int oi = ri[t + s2];
            if (ov > rv[t] || (ov == rv[t] && oi < ri[t])) { rv[t] = ov; ri[t] = oi; }
        }
        __syncthreads();
    }
    if (t == 0) {
        unsigned u = __float_as_uint(rv[0]);
        unsigned ord = (u & 0x80000000u) ? ~u : (u | 0x80000000u);
        unsigned long long key =
            ((unsigned long long)ord << 32) | (unsigned long long)(0xFFFFFFFFu - (unsigned)ri[0]);
        atomicMax(fixb + (size_t)b * NPIX + lrow, key);
    }
}

__global__ void k_fixapply(const int* __restrict__ flag,
                           const unsigned long long* __restrict__ fixb,
                           int* __restrict__ idx) {
    int t = blockIdx.x * 256 + threadIdx.x;
    if (t >= 2 * NPIX) return;
    if (flag[t]) idx[t] = (int)(0xFFFFFFFFu - (unsigned)(fixb[t] & 0xFFFFFFFFull));
}

// ---------------- stage 3a: per-(b,pixel) 9 source offsets ----------------
__global__ void k_soff(const int* __restrict__ idx, int* __restrict__ soff) {
    int t = blockIdx.x * 256 + threadIdx.x;
    if (t >= 2 * NPIX) return;
    int b = t / NPIX, pix = t - b * NPIX;
    int y = pix / 48, x = pix % 48;
#pragma unroll
    for (int i = 0; i < 3; ++i) {
#pragma unroll
        for (int j = 0; j < 3; ++j) {
            int u = i * 3 + j;
            int yq = y + 1 - i, xq = x + 1 - j;
            int so = -1;
            if (yq >= 0 && yq < 48 && xq >= 0 && xq < 48) {
                int m = idx[b * NPIX + yq * 48 + xq];
                int my = m / 48, mx = m % 48;
                int yy = my + i - 1, xx = mx + j - 1;
                if (yy >= 0 && yy < 48 && xx >= 0 && xx < 48) so = yy * 48 + xx;
            }
            soff[(b * 9 + u) * NPIX + pix] = so;
        }
    }
}

// ---------------- stage 3b: gather + fold via LDS-staged plane ----------------
#define CPB 4
__global__ __launch_bounds__(256) void k_out2(const float* __restrict__ x3,
                                              const int* __restrict__ soff,
                                              float* __restrict__ out) {
    __shared__ __align__(16) float plane[NPIX];
    const int t = threadIdx.x;
    const int img = blockIdx.x;
    const int b = img / 25, a = img % 25;

    int po[9][9];
#pragma unroll
    for (int u = 0; u < 9; ++u) {
        const int* sb = soff + (b * 9 + u) * NPIX;
#pragma unroll
        for (int k = 0; k < 9; ++k)
            po[k][u] = sb[k * 256 + t];
    }

    const size_t pbase = (size_t)b * 64 * 57600 + (size_t)a * 2304 +
                         (size_t)(blockIdx.y * CPB) * 57600;
    const float* gsrc = x3 + pbase;
    float* gdst = out + pbase;

    float4 r0, r1, r2;
    {
        const float4* g = (const float4*)gsrc;
        r0 = g[t]; r1 = g[t + 256];
        if (t < 64) r2 = g[t + 512];
    }
    float4* pl4 = (float4*)plane;
    pl4[t] = r0; pl4[t + 256] = r1;
    if (t < 64) pl4[t + 512] = r2;
    __syncthreads();

    for (int c = 0; c < CPB; ++c) {
        if (c + 1 < CPB) {
            const float4* g = (const float4*)(gsrc + (size_t)(c + 1) * 57600);
            r0 = g[t]; r1 = g[t + 256];
            if (t < 64) r2 = g[t + 512];
        }
        float* dst = gdst + (size_t)c * 57600;
#pragma unroll
        for (int k = 0; k < 9; ++k) {
            float acc = 0.f;
#pragma unroll
            for (int u = 0; u < 9; ++u) {
                int off = po[k][u];
                int ao = off < 0 ? 0 : off;
                float v = plane[ao];
                acc += (off < 0) ? 0.f : v;
            }
            dst[k * 256 + t] = acc;
        }
        __syncthreads();
        if (c + 1 < CPB) {
            pl4[t] = r0; pl4[t + 256] = r1;
            if (t < 64) pl4[t + 512] = r2;
        }
        __syncthreads();
    }
}

extern "C" void kernel_launch(void* const* d_in, const int* in_sizes, int n_in,
                              void* d_out, int out_size, void* d_ws, size_t ws_size,
                              hipStream_t stream) {
    const float* x1 = (const float*)d_in[0];
    const float* x2 = (const float*)d_in[1];
    const float* x3 = (const float*)d_in[2];
    const float* W  = (const float*)d_in[3];
    float* ws = (float*)d_ws;

    float* qp    = ws + OFF_QP;
    float* kp    = ws + OFF_KP;
    float* nk    = ws + OFF_NK;
    float* invNk = ws + OFF_INVNK;
    float* pval  = ws + OFF_PVAL;
    float* psec  = ws + OFF_PSEC;
    int*   pidx  = (int*)(ws + OFF_PIDX);
    int*   idx   = (int*)(ws + OFF_IDX);
    int*   flag  = (int*)(ws + OFF_FLAG);
    unsigned long long* fixb = (unsigned long long*)(ws + OFF_FIXB);
    float* S     = ws + OFF_S;
    int*   soff  = (int*)(ws + OFF_SOFF);
    float* out   = (float*)d_out;

    const bool bigS = ws_size >= (size_t)(OFF_S + 2UL * (unsigned long)SSTRIDE) * 4UL;

    // zero qp+kp (padding rows/cols) and fixb
    hipMemsetAsync(qp, 0, (size_t)4 * PLANE * sizeof(float), stream);
    hipMemsetAsync(fixb, 0, (size_t)2 * NPIX * 8, stream);

    k_qk<<<450, 256, 0, stream>>>(x1, x2, W, qp, kp);
    k_nk<<<(2 * NPAD + 255) / 256, 256, 0, stream>>>(kp, nk);
    k_invnk<<<(2 * NPIX + 255) / 256, 256, 0, stream>>>(nk, invNk);

    if (bigS) {
        k_mfma<<<dim3(20, 20, 2), 256, 0, stream>>>(qp, kp, S, SSTRIDE, 0);
        k_argmax<<<dim3(48, 48, 2), 384, 0, stream>>>(S, invNk, pval, psec, pidx, SSTRIDE, 0);
    } else {
        for (int b = 0; b < 2; ++b) {
            k_mfma<<<dim3(20, 20, 1), 256, 0, stream>>>(qp, kp, S, 0L, b);
            k_argmax<<<dim3(48, 48, 1), 384, 0, stream>>>(S, invNk, pval, psec, pidx, 0L, b);
        }
    }
    k_argred<<<(2 * NPIX + 255) / 256, 256, 0, stream>>>(pval, psec, pidx, idx, flag);
    k_fix<<<dim3(NPIX, 2, 2), 256, 0, stream>>>(qp, kp, invNk, flag, fixb);
    k_fixapply<<<(2 * NPIX + 255) / 256, 256, 0, stream>>>(flag, fixb, idx);
    k_soff<<<(2 * NPIX + 255) / 256, 256, 0, stream>>>(idx, soff);
    k_out2<<<dim3(50, 16), 256, 0, stream>>>(x3, soff, out);
}

// Round 8
// 232.190 us; speedup vs baseline: 1.0647x; 1.0647x over previous
//
#include <hip/hip_runtime.h>
#include <math.h>
#include <float.h>

#define NPIX 2304   // 48*48
#define NPAD 2500   // 50*50
#define PLANE 573440  // 2560*224 padded [p][d] plane per batch
#define MARGIN 3e-4f

// ws layout in floats
#define OFF_QP    0u          // [2][2560][224] fp32, p-major, zero-padded
#define OFF_KP    1146880u    // [2][2560][224]
#define OFF_NK    2293760u    // [2][2500]
#define OFF_INVNK 2298760u    // [2][2304]
#define OFF_PVAL  2303368u    // [2][48][2304] partial best
#define OFF_PSEC  2524552u    // [2][48][2304] partial second-best
#define OFF_PIDX  2745736u    // int [2][48][2304]
#define OFF_IDX   2966920u    // int [2][2304]
#define OFF_FLAG  2971528u    // int [2][2304]
#define OFF_S     2985352u    // [z][2500][2500]
#define OFF_SOFF  OFF_S       // int [2][9][2304] — aliases S (S dead by then)
#define SSTRIDE   6250000L

typedef __attribute__((ext_vector_type(8))) short short8;
typedef __attribute__((ext_vector_type(4))) float f32x4;

__device__ __forceinline__ unsigned short bfhi(float f) {
    unsigned u = __float_as_uint(f);
    return (unsigned short)((u + 0x7FFFu + ((u >> 16) & 1u)) >> 16);
}
__device__ __forceinline__ unsigned short bfcvt(float f, bool wantHi) {
    unsigned short h = bfhi(f);
    if (wantHi) return h;
    float hf = __uint_as_float(((unsigned)h) << 16);
    return bfhi(f - hf);
}

// ---------------- stage 1: q = W*x1, k = W*x2 -> [p][d] rows ----------------
__global__ __launch_bounds__(256) void k_qk(const float* __restrict__ x1,
                                            const float* __restrict__ x2,
                                            const float* __restrict__ W,
                                            float* __restrict__ qp,
                                            float* __restrict__ kp) {
    __shared__ float Ws[512];
    const int t = threadIdx.x;
    Ws[t] = W[t];
    Ws[t + 256] = W[t + 256];
    __syncthreads();
    const int img = blockIdx.x / 9;      // 0..49  (b*25 + a)
    const int chunk = blockIdx.x % 9;
    const int pix = chunk * 256 + t;     // 0..2303
    const int b = img / 25, a = img % 25;
    const int y = pix / 48, x = pix % 48;

    float q[8], k[8];
#pragma unroll
    for (int o = 0; o < 8; ++o) { q[o] = 0.f; k[o] = 0.f; }

    const float* p1 = x1 + (size_t)b * 64 * 57600 + a * 2304 + pix;
    const float* p2 = x2 + (size_t)b * 64 * 57600 + a * 2304 + pix;
    for (int c = 0; c < 64; ++c) {
        float v1 = p1[c * 57600];
        float v2 = p2[c * 57600];
#pragma unroll
        for (int o = 0; o < 8; ++o) {
            float w = Ws[o * 64 + c];
            q[o] = fmaf(w, v1, q[o]);
            k[o] = fmaf(w, v2, k[o]);
        }
    }
    const int p = (y + 1) * 50 + (x + 1);
    float* qd = qp + (size_t)b * PLANE + (size_t)p * 224 + a * 8;
    float* kd = kp + (size_t)b * PLANE + (size_t)p * 224 + a * 8;
    float4 q0 = { q[0], q[1], q[2], q[3] }, q1 = { q[4], q[5], q[6], q[7] };
    float4 k0 = { k[0], k[1], k[2], k[3] }, k1 = { k[4], k[5], k[6], k[7] };
    *(float4*)qd = q0; *(float4*)(qd + 4) = q1;
    *(float4*)kd = k0; *(float4*)(kd + 4) = k1;
}

// ---------------- per-position squared norms of k ----------------
__global__ void k_nk(const float* __restrict__ kp, float* __restrict__ nk) {
    int t = blockIdx.x * 256 + threadIdx.x;  // 0..4999
    if (t >= 2 * NPAD) return;
    int b = t / NPAD, p = t - b * NPAD;
    const float* src = kp + (size_t)b * PLANE + (size_t)p * 224;
    float s = 0.f;
    for (int d = 0; d < 200; d += 4) {
        float4 v = *(const float4*)(src + d);
        s = fmaf(v.x, v.x, s); s = fmaf(v.y, v.y, s);
        s = fmaf(v.z, v.z, s); s = fmaf(v.w, v.w, s);
    }
    nk[t] = s;
}

__global__ void k_invnk(const float* __restrict__ nk, float* __restrict__ invNk) {
    int t = blockIdx.x * 256 + threadIdx.x;  // 0..4607
    if (t >= 2 * NPIX) return;
    int b = t / NPIX, m = t - b * NPIX;
    int my = m / 48, mx = m % 48;
    const float* nb = nk + b * NPAD;
    float s = 0.f;
#pragma unroll
    for (int i = 0; i < 3; ++i)
#pragma unroll
        for (int j = 0; j < 3; ++j)
            s += nb[(my + i) * 50 + mx + j];
    invNk[t] = 1.0f / fmaxf(sqrtf(s), 1e-12f);
}

// ---- stage 2a: S ~= A^T B via 3-term bf16-split MFMA (hi*hi + hi*lo + lo*hi) ----
__global__ __launch_bounds__(256, 2) void k_mfma(const float* __restrict__ qp,
                                                 const float* __restrict__ kp,
                                                 float* __restrict__ S,
                                                 long sStride, int bofs) {
    __shared__ short Abuf[2][4096];   // 128 rows x 32 d (bf16)
    __shared__ short Bbuf[2][4096];
    const int t = threadIdx.x;
    const int nwg = gridDim.x * gridDim.y * gridDim.z;
    const int lin = (blockIdx.z * gridDim.y + blockIdx.y) * gridDim.x + blockIdx.x;
    const int work = (lin & 7) * (nwg >> 3) + (lin >> 3);
    const int z = work / 400;
    const int rem = work - z * 400;
    const int wy = rem / 20, wx = rem - (rem / 20) * 20;

    const int batch = bofs + z;
    const float* A = qp + (size_t)batch * PLANE;
    const float* B = kp + (size_t)batch * PLANE;
    float* Sb = S + (size_t)z * sStride;
    const int p0 = wy * 128, r0 = wx * 128;

    const int srow = t >> 2, squad = t & 3;
    const int spq = squad ^ (srow & 3);

    const int w = t >> 6, l = t & 63;
    const int wqp = (w >> 1) * 64, wqr = (w & 1) * 64;
    const int lp = l & 15;
    const int physq = (l >> 4) ^ (l & 3);

    f32x4 acc[4][4];
#pragma unroll
    for (int i = 0; i < 4; ++i)
#pragma unroll
        for (int j = 0; j < 4; ++j) acc[i][j] = (f32x4){0.f, 0.f, 0.f, 0.f};

    float4 ra0, ra1, ra2, ra3, rb0, rb1, rb2, rb3;

#define LOADS(ks)                                                              \
    {                                                                          \
        const int d0 = ((ks) % 7) * 32 + squad * 8;                            \
        const float* ap = A + (size_t)(p0 + srow) * 224 + d0;                  \
        const float* bp = B + (size_t)(r0 + srow) * 224 + d0;                  \
        ra0 = *(const float4*)ap;       ra1 = *(const float4*)(ap + 4);        \
        ra2 = *(const float4*)(ap + 64 * 224); ra3 = *(const float4*)(ap + 64 * 224 + 4); \
        rb0 = *(const float4*)bp;       rb1 = *(const float4*)(bp + 4);        \
        rb2 = *(const float4*)(bp + 64 * 224); rb3 = *(const float4*)(bp + 64 * 224 + 4); \
    }

#define PACK8(dst, v0, v1, useHi)                                              \
    {                                                                          \
        short8 vv;                                                             \
        vv[0] = (short)bfcvt(v0.x, useHi); vv[1] = (short)bfcvt(v0.y, useHi);  \
        vv[2] = (short)bfcvt(v0.z, useHi); vv[3] = (short)bfcvt(v0.w, useHi);  \
        vv[4] = (short)bfcvt(v1.x, useHi); vv[5] = (short)bfcvt(v1.y, useHi);  \
        vv[6] = (short)bfcvt(v1.z, useHi); vv[7] = (short)bfcvt(v1.w, useHi);  \
        *(short8*)(dst) = vv;                                                  \
    }

#define WRITE(buf, ks)                                                         \
    {                                                                          \
        const int term = (ks) / 7;                                             \
        const bool aHi = (term < 2), bHi = (term != 1);                        \
        PACK8(&Abuf[buf][srow * 32 + spq * 8], ra0, ra1, aHi);                 \
        PACK8(&Abuf[buf][(64 + srow) * 32 + spq * 8], ra2, ra3, aHi);          \
        PACK8(&Bbuf[buf][srow * 32 + spq * 8], rb0, rb1, bHi);                 \
        PACK8(&Bbuf[buf][(64 + srow) * 32 + spq * 8], rb2, rb3, bHi);          \
    }

    LOADS(0);
    WRITE(0, 0);
    __syncthreads();

    for (int ks = 0; ks < 21; ++ks) {
        const int cur = ks & 1;
        if (ks + 1 < 21) LOADS(ks + 1);
        {
            const short* Ab = &Abuf[cur][0];
            const short* Bb = &Bbuf[cur][0];
            short8 af[4], bfr[4];
#pragma unroll
            for (int tr = 0; tr < 4; ++tr)
                af[tr] = *(const short8*)(Ab + (wqp + tr * 16 + lp) * 32 + physq * 8);
#pragma unroll
            for (int tc = 0; tc < 4; ++tc)
                bfr[tc] = *(const short8*)(Bb + (wqr + tc * 16 + lp) * 32 + physq * 8);
#pragma unroll
            for (int tr = 0; tr < 4; ++tr)
#pragma unroll
                for (int tc = 0; tc < 4; ++tc)
                    acc[tr][tc] = __builtin_amdgcn_mfma_f32_16x16x32_bf16(
                        af[tr], bfr[tc], acc[tr][tc], 0, 0, 0);
        }
        if (ks + 1 < 21) {
            WRITE(cur ^ 1, ks + 1);
            __syncthreads();
        }
    }

#pragma unroll
    for (int tr = 0; tr < 4; ++tr) {
#pragma unroll
        for (int v = 0; v < 4; ++v) {
            const int p = p0 + wqp + tr * 16 + (l >> 4) * 4 + v;
            if (p < NPAD) {
                float* srow_ = Sb + (size_t)p * NPAD;
#pragma unroll
                for (int tc = 0; tc < 4; ++tc) {
                    const int c = r0 + wqr + tc * 16 + lp;
                    if (c < NPAD) srow_[c] = acc[tr][tc][v];
                }
            }
        }
    }
#undef LOADS
#undef PACK8
#undef WRITE
}

// -------- stage 2b: block per (my, ly, z); box-sum + partial top-2 argmax --------
__global__ __launch_bounds__(384) void k_argmax(const float* __restrict__ S,
                                                const float* __restrict__ invNk,
                                                float* __restrict__ pval,
                                                float* __restrict__ psec,
                                                int* __restrict__ pidx,
                                                long sStride, int bofs) {
    __shared__ float band[3][50][50];
    const int t = threadIdx.x;
    const int my = blockIdx.x;     // 0..47
    const int ly = blockIdx.y;     // 0..47
    const int batch = bofs + blockIdx.z;
    const float* Sb = S + (size_t)blockIdx.z * sStride;
    const int lx = t >> 3;         // 0..47
    const int mc = t & 7;          // 0..7

    for (int e = t; e < 7500; e += 384) {
        int i = e / 2500;
        int rem = e - i * 2500;
        int uu = rem / 50;
        int vv = rem - uu * 50;
        band[i][uu][vv] = Sb[(size_t)((ly + i) * 50 + uu) * NPAD + (my + i) * 50 + vv];
    }
    __syncthreads();

    const float* inb = invNk + batch * NPIX;
    float b1 = -FLT_MAX, b2 = -FLT_MAX;
    int i1 = 0x7FFFFFFF;

#pragma unroll
    for (int k = 0; k < 6; ++k) {
        int mx = mc + (k << 3);
        float s = 0.f;
#pragma unroll
        for (int i = 0; i < 3; ++i)
#pragma unroll
            for (int j = 0; j < 3; ++j)
                s += band[i][lx + j][mx + j];
        int m = my * 48 + mx;
        float v = s * inb[m];
        if (v > b1 || (v == b1 && m < i1)) { b2 = b1; b1 = v; i1 = m; }
        else b2 = fmaxf(b2, v);
    }
#pragma unroll
    for (int off = 1; off < 8; off <<= 1) {
        float ob1 = __shfl_xor(b1, off, 64);
        int oi1 = __shfl_xor(i1, off, 64);
        float ob2 = __shfl_xor(b2, off, 64);
        if (ob1 > b1 || (ob1 == b1 && oi1 < i1)) { b2 = fmaxf(b1, ob2); b1 = ob1; i1 = oi1; }
        else b2 = fmaxf(b2, ob1);
    }
    if (mc == 0) {
        int o = (batch * 48 + my) * NPIX + ly * 48 + lx;
        pval[o] = b1;
        psec[o] = b2;
        pidx[o] = i1;
    }
}

// per-batch merge over my partials
__global__ void k_argred(const float* __restrict__ pval, const float* __restrict__ psec,
                         const int* __restrict__ pidx, int* __restrict__ idxout,
                         int* __restrict__ flag, int b) {
    int lcl = blockIdx.x * 256 + threadIdx.x;
    if (lcl >= NPIX) return;
    float b1 = -FLT_MAX, b2 = -FLT_MAX;
    int i1 = 0x7FFFFFFF;
    for (int my = 0; my < 48; ++my) {
        int o = (b * 48 + my) * NPIX + lcl;
        float v1 = pval[o], v2 = psec[o];
        int ii = pidx[o];
        if (v1 > b1 || (v1 == b1 && ii < i1)) { b2 = fmaxf(b1, v2); b1 = v1; i1 = ii; }
        else b2 = fmaxf(b2, v1);
    }
    idxout[b * NPIX + lcl] = i1;
    flag[b * NPIX + lcl] = (b1 - b2 < MARGIN) ? 1 : 0;
}

// -------- candidate-pruned exact recheck: one wave per flagged row --------
__global__ __launch_bounds__(256) void k_fix2(const float* __restrict__ qp,
                                              const float* __restrict__ kp,
                                              const float* __restrict__ S,
                                              const float* __restrict__ invNk,
                                              const float* __restrict__ pval,
                                              const float* __restrict__ psec,
                                              const int* __restrict__ pidx,
                                              const int* __restrict__ flag,
                                              int* __restrict__ idx,
                                              long sStride, int bofs) {
    const int t = threadIdx.x;
    const int lane = t & 63;
    const int row = blockIdx.x * 4 + (t >> 6);
    const int z = blockIdx.y;
    const int b = bofs + z;
    if (!flag[b * NPIX + row]) return;
    const float* Sb = S + (size_t)z * sStride;
    const float* Ap = qp + (size_t)b * PLANE;
    const float* Bp = kp + (size_t)b * PLANE;
    const float* inb = invNk + b * NPIX;
    const int ly = row / 48, lx = row % 48;

    // merged approx top value over this row's my-partials
    float v1 = -FLT_MAX, v2 = -FLT_MAX;
    if (lane < 48) {
        int o = (b * 48 + lane) * NPIX + row;
        v1 = pval[o];
        v2 = psec[o];
    }
    float bb = v1;
#pragma unroll
    for (int off = 1; off < 64; off <<= 1)
        bb = fmaxf(bb, __shfl_xor(bb, off, 64));
    const float th = bb - MARGIN;

    // candidate my blocks: any block whose top-2 reaches th (sound: a value >= th
    // in a block is that block's v1 or v2 unless two better values >= th exist,
    // in which case those two are candidates themselves)
    unsigned long long mask = __ballot(lane < 48 && (v1 >= th || v2 >= th));
    float eb = -FLT_MAX;
    int ebi = 0x7FFFFFFF;
    while (mask) {
        const int my = __ffsll((long long)mask) - 1;
        mask &= mask - 1;
        // approx box-sums for the 48 mx of this my — bit-identical op order to k_argmax
        float va = -FLT_MAX;
        if (lane < 48) {
            float s = 0.f;
#pragma unroll
            for (int i = 0; i < 3; ++i)
#pragma unroll
                for (int j = 0; j < 3; ++j)
                    s += Sb[(size_t)((ly + i) * 50 + lx + j) * NPAD + (my + i) * 50 + lane + j];
            va = s * inb[my * 48 + lane];
        }
        unsigned long long m2 = __ballot(lane < 48 && va >= th);
        while (m2) {
            const int mx = __ffsll((long long)m2) - 1;
            m2 &= m2 - 1;
            const int m = my * 48 + mx;
            // exact fp32 rescore: 9 window dots over d, lane-strided + tree reduce
            float part = 0.f;
#pragma unroll
            for (int ij = 0; ij < 9; ++ij) {
                const float* qr = Ap + (size_t)((ly + ij / 3) * 50 + lx + ij % 3) * 224;
                const float* kr = Bp + (size_t)((my + ij / 3) * 50 + mx + ij % 3) * 224;
                for (int d = lane; d < 200; d += 64)
                    part = fmaf(qr[d], kr[d], part);
            }
#pragma unroll
            for (int off = 1; off < 64; off <<= 1)
                part += __shfl_xor(part, off, 64);
            const float v = part * inb[m];
            if (v > eb) { eb = v; ebi = m; }  // ascending m scan -> min-m tie-break
        }
    }
    if (lane == 0 && ebi != 0x7FFFFFFF) idx[b * NPIX + row] = ebi;
}

// ---------------- stage 3a: per-(b,pixel) 9 source offsets ----------------
__global__ void k_soff(const int* __restrict__ idx, int* __restrict__ soff) {
    int t = blockIdx.x * 256 + threadIdx.x;
    if (t >= 2 * NPIX) return;
    int b = t / NPIX, pix = t - b * NPIX;
    int y = pix / 48, x = pix % 48;
#pragma unroll
    for (int i = 0; i < 3; ++i) {
#pragma unroll
        for (int j = 0; j < 3; ++j) {
            int u = i * 3 + j;
            int yq = y + 1 - i, xq = x + 1 - j;
            int so = -1;
            if (yq >= 0 && yq < 48 && xq >= 0 && xq < 48) {
                int m = idx[b * NPIX + yq * 48 + xq];
                int my = m / 48, mx = m % 48;
                int yy = my + i - 1, xx = mx + j - 1;
                if (yy >= 0 && yy < 48 && xx >= 0 && xx < 48) so = yy * 48 + xx;
            }
            soff[(b * 9 + u) * NPIX + pix] = so;
        }
    }
}

// ---------------- stage 3b: gather + fold via LDS-staged plane ----------------
#define CPB 4
__global__ __launch_bounds__(256) void k_out2(const float* __restrict__ x3,
                                              const int* __restrict__ soff,
                                              float* __restrict__ out) {
    __shared__ __align__(16) float plane[NPIX];
    const int t = threadIdx.x;
    const int img = blockIdx.x;
    const int b = img / 25, a = img % 25;

    int po[9][9];
#pragma unroll
    for (int u = 0; u < 9; ++u) {
        const int* sb = soff + (b * 9 + u) * NPIX;
#pragma unroll
        for (int k = 0; k < 9; ++k)
            po[k][u] = sb[k * 256 + t];
    }

    const size_t pbase = (size_t)b * 64 * 57600 + (size_t)a * 2304 +
                         (size_t)(blockIdx.y * CPB) * 57600;
    const float* gsrc = x3 + pbase;
    float* gdst = out + pbase;

    float4 r0, r1, r2;
    {
        const float4* g = (const float4*)gsrc;
        r0 = g[t]; r1 = g[t + 256];
        if (t < 64) r2 = g[t + 512];
    }
    float4* pl4 = (float4*)plane;
    pl4[t] = r0; pl4[t + 256] = r1;
    if (t < 64) pl4[t + 512] = r2;
    __syncthreads();

    for (int c = 0; c < CPB; ++c) {
        if (c + 1 < CPB) {
            const float4* g = (const float4*)(gsrc + (size_t)(c + 1) * 57600);
            r0 = g[t]; r1 = g[t + 256];
            if (t < 64) r2 = g[t + 512];
        }
        float* dst = gdst + (size_t)c * 57600;
#pragma unroll
        for (int k = 0; k < 9; ++k) {
            float acc = 0.f;
#pragma unroll
            for (int u = 0; u < 9; ++u) {
                int off = po[k][u];
                int ao = off < 0 ? 0 : off;
                float v = plane[ao];
                acc += (off < 0) ? 0.f : v;
            }
            dst[k * 256 + t] = acc;
        }
        __syncthreads();
        if (c + 1 < CPB) {
            pl4[t] = r0; pl4[t + 256] = r1;
            if (t < 64) pl4[t + 512] = r2;
        }
        __syncthreads();
    }
}

extern "C" void kernel_launch(void* const* d_in, const int* in_sizes, int n_in,
                              void* d_out, int out_size, void* d_ws, size_t ws_size,
                              hipStream_t stream) {
    const float* x1 = (const float*)d_in[0];
    const float* x2 = (const float*)d_in[1];
    const float* x3 = (const float*)d_in[2];
    const float* W  = (const float*)d_in[3];
    float* ws = (float*)d_ws;

    float* qp    = ws + OFF_QP;
    float* kp    = ws + OFF_KP;
    float* nk    = ws + OFF_NK;
    float* invNk = ws + OFF_INVNK;
    float* pval  = ws + OFF_PVAL;
    float* psec  = ws + OFF_PSEC;
    int*   pidx  = (int*)(ws + OFF_PIDX);
    int*   idx   = (int*)(ws + OFF_IDX);
    int*   flag  = (int*)(ws + OFF_FLAG);
    float* S     = ws + OFF_S;
    int*   soff  = (int*)(ws + OFF_SOFF);
    float* out   = (float*)d_out;

    const bool bigS = ws_size >= (size_t)(OFF_S + 2UL * (unsigned long)SSTRIDE) * 4UL;

    // zero qp+kp (padding rows/cols)
    hipMemsetAsync(qp, 0, (size_t)4 * PLANE * sizeof(float), stream);

    k_qk<<<450, 256, 0, stream>>>(x1, x2, W, qp, kp);
    k_nk<<<(2 * NPAD + 255) / 256, 256, 0, stream>>>(kp, nk);
    k_invnk<<<(2 * NPIX + 255) / 256, 256, 0, stream>>>(nk, invNk);

    if (bigS) {
        k_mfma<<<dim3(20, 20, 2), 256, 0, stream>>>(qp, kp, S, SSTRIDE, 0);
        k_argmax<<<dim3(48, 48, 2), 384, 0, stream>>>(S, invNk, pval, psec, pidx, SSTRIDE, 0);
        k_argred<<<9, 256, 0, stream>>>(pval, psec, pidx, idx, flag, 0);
        k_argred<<<9, 256, 0, stream>>>(pval, psec, pidx, idx, flag, 1);
        k_fix2<<<dim3(576, 2), 256, 0, stream>>>(qp, kp, S, invNk, pval, psec, pidx,
                                                 flag, idx, SSTRIDE, 0);
    } else {
        for (int b = 0; b < 2; ++b) {
            k_mfma<<<dim3(20, 20, 1), 256, 0, stream>>>(qp, kp, S, 0L, b);
            k_argmax<<<dim3(48, 48, 1), 384, 0, stream>>>(S, invNk, pval, psec, pidx, 0L, b);
            k_argred<<<9, 256, 0, stream>>>(pval, psec, pidx, idx, flag, b);
            k_fix2<<<dim3(576, 1), 256, 0, stream>>>(qp, kp, S, invNk, pval, psec, pidx,
                                                     flag, idx, 0L, b);
        }
    }
    k_soff<<<(2 * NPIX + 255) / 256, 256, 0, stream>>>(idx, soff);
    k_out2<<<dim3(50, 16), 256, 0, stream>>>(x3, soff, out);
}